// Round 4
// baseline (2865.032 us; speedup 1.0000x reference)
//
#include <hip/hip_runtime.h>
#include <math.h>

typedef unsigned short u16;
using short8  = __attribute__((ext_vector_type(8))) short;
using float4v = __attribute__((ext_vector_type(4))) float;

__device__ __forceinline__ float b2f(u16 u) {
    union { unsigned int i; float f; } v; v.i = ((unsigned int)u) << 16; return v.f;
}
__device__ __forceinline__ u16 f2b(float f) {
    union { float f; unsigned int i; } v; v.f = f;
    unsigned int x = v.i;
    unsigned int r = (x + 0x7fffu + ((x >> 16) & 1u)) >> 16;
    return (u16)r;
}

// ---------------------------------------------------------------------------
// weight f32 -> bf16 conversion (grid-stride)
// ---------------------------------------------------------------------------
__global__ __launch_bounds__(256) void wcvt(const float* __restrict__ s,
                                            u16* __restrict__ d, int n) {
    int stride = gridDim.x * 256;
    for (int i = blockIdx.x * 256 + threadIdx.x; i < n; i += stride)
        d[i] = f2b(s[i]);
}

// ---------------------------------------------------------------------------
// mix_shift: out[i,d] = f[d]*xn_i[d] + (1-f[d])*xn_{i-1}[d]  (bf16 out)
// xn = w*src*inv_rmsnorm; src is f32; norms computed in-block (f32).
// ---------------------------------------------------------------------------
__global__ __launch_bounds__(256) void mix_shift(const float* __restrict__ src,
                                                 const float* __restrict__ w,
                                                 const float* __restrict__ f,
                                                 u16* __restrict__ out) {
    __shared__ float redc[256], redp[256];
    int tid = threadIdx.x;
    size_t i = blockIdx.x;
    size_t ip = ((i & 4095) == 0) ? i : i - 1;
    float xc[4], xp[4];
    float ssc = 0.f, ssp = 0.f;
#pragma unroll
    for (int l = 0; l < 4; ++l) {
        int d = tid + l * 256;
        xc[l] = src[i * 1024 + d];  ssc += xc[l] * xc[l];
        xp[l] = src[ip * 1024 + d]; ssp += xp[l] * xp[l];
    }
    redc[tid] = ssc; redp[tid] = ssp; __syncthreads();
    for (int st = 128; st > 0; st >>= 1) {
        if (tid < st) { redc[tid] += redc[tid + st]; redp[tid] += redp[tid + st]; }
        __syncthreads();
    }
    float ic  = 1.f / (sqrtf(redc[0]) * (1.f / 32.f) + 1e-8f);
    float ipv = 1.f / (sqrtf(redp[0]) * (1.f / 32.f) + 1e-8f);
#pragma unroll
    for (int l = 0; l < 4; ++l) {
        int d = tid + l * 256;
        float wd = w[d], fd = f[d];
        float xn = wd * xc[l] * ic;
        float xx = wd * xp[l] * ipv;
        out[i * 1024 + d] = f2b(fd * xn + (1.f - fd) * xx);
    }
}

// ---------------------------------------------------------------------------
// kproj (f64): per token j, K[j,:] = (w1*x_j*inv_j) @ kw^T + kb  -> f32 Kt
// Also stores invn[j] (f32). Precision-critical for top-k selection.
// ---------------------------------------------------------------------------
__global__ __launch_bounds__(256) void kproj(const float* __restrict__ x,
                                             const float* __restrict__ w1,
                                             const float* __restrict__ kw,
                                             const float* __restrict__ kb,
                                             float* __restrict__ Kt,
                                             float* __restrict__ invn) {
    __shared__ double xk[1024];
    __shared__ double red[256];
    int tid = threadIdx.x;
    size_t j = blockIdx.x;
    double ss = 0.0;
    float xc[4];
#pragma unroll
    for (int l = 0; l < 4; ++l) {
        int d = tid + l * 256;
        xc[l] = x[j * 1024 + d];
        ss += (double)xc[l] * (double)xc[l];
    }
    red[tid] = ss; __syncthreads();
    for (int st = 128; st > 0; st >>= 1) {
        if (tid < st) red[tid] += red[tid + st];
        __syncthreads();
    }
    double inv = 1.0 / (sqrt(red[0]) * (1.0 / 32.0) + 1e-8);
#pragma unroll
    for (int l = 0; l < 4; ++l) {
        int d = tid + l * 256;
        xk[d] = (double)w1[d] * (double)xc[l] * inv;
    }
    __syncthreads();
    int wv = tid >> 6, lane = tid & 63;
    for (int it = 0; it < 16; ++it) {
        int a = wv * 16 + it;
        const float* kr = kw + (size_t)a * 1024;
        double p = 0.0;
#pragma unroll
        for (int m = 0; m < 16; ++m) p += xk[lane + 64 * m] * (double)kr[lane + 64 * m];
        for (int off = 32; off; off >>= 1) p += __shfl_xor(p, off);
        if (lane == 0) Kt[j * 64 + a] = (float)(p + (double)kb[a]);
    }
    if (tid == 0) invn[j] = (float)inv;
}

// ---------------------------------------------------------------------------
// attn: per query i — Q_i (f64) in-block, f64 scores vs 4096 f32 K rows,
// iterative top-32 (tie -> lower index), softmax, y_i = w1 .* P@(x*inv) (bf16).
// ---------------------------------------------------------------------------
__global__ __launch_bounds__(256) void attn_topk(const float* __restrict__ x,
                                                 const float* __restrict__ w1,
                                                 const float* __restrict__ qw,
                                                 const float* __restrict__ qb,
                                                 const float* __restrict__ Kt,
                                                 const float* __restrict__ invn,
                                                 u16* __restrict__ y) {
    __shared__ double xq[1024];
    __shared__ double qv[64];
    __shared__ double sc[4096];
    __shared__ double rv[256];
    __shared__ int    ri[256];
    __shared__ double topv[32];
    __shared__ int    topi[32];
    __shared__ float  pw[32];
    __shared__ double red[256];
    int tid = threadIdx.x;
    int i = blockIdx.x;
    int base = (i >> 12) << 12;
    float xc[4];
    double ss = 0.0;
#pragma unroll
    for (int l = 0; l < 4; ++l) {
        int d = tid + l * 256;
        xc[l] = x[(size_t)i * 1024 + d];
        ss += (double)xc[l] * (double)xc[l];
    }
    red[tid] = ss; __syncthreads();
    for (int st = 128; st > 0; st >>= 1) {
        if (tid < st) red[tid] += red[tid + st];
        __syncthreads();
    }
    double inv = 1.0 / (sqrt(red[0]) * (1.0 / 32.0) + 1e-8);
#pragma unroll
    for (int l = 0; l < 4; ++l) {
        int d = tid + l * 256;
        xq[d] = (double)w1[d] * (double)xc[l] * inv;
    }
    __syncthreads();
    int wv = tid >> 6, lane = tid & 63;
    for (int it = 0; it < 16; ++it) {
        int a = wv * 16 + it;
        const float* qr = qw + (size_t)a * 1024;
        double p = 0.0;
#pragma unroll
        for (int m = 0; m < 16; ++m) p += xq[lane + 64 * m] * (double)qr[lane + 64 * m];
        for (int off = 32; off; off >>= 1) p += __shfl_xor(p, off);
        if (lane == 0) qv[a] = p + (double)qb[a];
    }
    __syncthreads();
    const float* Kb_ = Kt + (size_t)base * 64;
    for (int j = tid; j < 4096; j += 256) {
        const float4* kr = (const float4*)(Kb_ + (size_t)j * 64);
        double a0 = 0.0, a1 = 0.0, a2 = 0.0, a3 = 0.0;
#pragma unroll
        for (int t = 0; t < 16; ++t) {
            float4 kv = kr[t];
            a0 += qv[4 * t + 0] * (double)kv.x; a1 += qv[4 * t + 1] * (double)kv.y;
            a2 += qv[4 * t + 2] * (double)kv.z; a3 += qv[4 * t + 3] * (double)kv.w;
        }
        double sv = (a0 + a1 + a2 + a3) * 0.125;
        sc[j] = (sv == sv) ? sv : -1e300;   // NaN insurance
    }
    __syncthreads();
    for (int it = 0; it < 32; ++it) {
        double lv = sc[tid]; int li = tid;
        for (int j = tid + 256; j < 4096; j += 256) {
            double v = sc[j];
            if (v > lv) { lv = v; li = j; }
        }
        rv[tid] = lv; ri[tid] = li;
        __syncthreads();
        for (int s2 = 128; s2 > 0; s2 >>= 1) {
            if (tid < s2) {
                double ov = rv[tid + s2]; int oi = ri[tid + s2];
                if (ov > rv[tid] || (ov == rv[tid] && oi < ri[tid])) { rv[tid] = ov; ri[tid] = oi; }
            }
            __syncthreads();
        }
        if (tid == 0) { topv[it] = rv[0]; topi[it] = ri[0]; sc[ri[0]] = -1.0e301; }
        __syncthreads();
    }
    if (tid == 0) {
        double m = topv[0], s = 0.0;
        double e[32];
#pragma unroll
        for (int j = 0; j < 32; ++j) { e[j] = exp(topv[j] - m); s += e[j]; }
        double invs = 1.0 / s;
#pragma unroll
        for (int j = 0; j < 32; ++j)
            pw[j] = (float)(e[j] * invs) * invn[base + topi[j]];
    }
    __syncthreads();
    float acc[4] = {0.f, 0.f, 0.f, 0.f};
    for (int j = 0; j < 32; ++j) {
        float pj = pw[j];
        const float* xr = x + (size_t)(base + topi[j]) * 1024;
#pragma unroll
        for (int l = 0; l < 4; ++l) acc[l] += pj * xr[tid + l * 256];
    }
#pragma unroll
    for (int l = 0; l < 4; ++l) {
        int d = tid + l * 256;
        y[(size_t)i * 1024 + d] = f2b(w1[d] * acc[l]);
    }
}

// ---------------------------------------------------------------------------
// MFMA bf16 GEMM: C[M,N] = A[M,K] @ B[N,K]^T. 128x128 tile, BK=64,
// 4 waves (2x2 of 64x64), 16x16x32 MFMA, vectorized LDS staging.
// EPI: 0 = bf16(acc + f32 bias[col])
//      1 = bf16(acc + bf16 aux0[g])              (in-place-safe)
//      2 = bf16(sigmoid(acc) * bf16 aux0[g])     (in-place-safe)
//      3 = f32: outF[g] = acc + f32 auxF[g]
//      4 = bf16(sigmoid(acc))
//      5 = bf16(relu(acc)^2)
//      6 = f32: outF[g] += bf16(aux0[g]) * acc   (read-modify-write)
// outB/outF may alias aux-inputs only at the SAME element index (same thread).
// ---------------------------------------------------------------------------
template <int EPI>
__global__ __launch_bounds__(256) void gemm_bt(const u16* __restrict__ A,
                                               const u16* __restrict__ B,
                                               u16* outB, float* outF,
                                               const float* __restrict__ biasF,
                                               const u16* aux0,
                                               const float* auxF,
                                               int N, int K, int lda, int ldb) {
    __shared__ u16 As[128 * 64];
    __shared__ u16 Bs[128 * 64];
    int tid = threadIdx.x;
    int lane = tid & 63;
    int wv = tid >> 6;
    int row0 = blockIdx.y * 128;
    int col0 = blockIdx.x * 128;
    int wm = (wv >> 1) * 64;
    int wn = (wv & 1) * 64;
    int frow = lane & 15, quad = lane >> 4;

    float4v zero = {0.f, 0.f, 0.f, 0.f};
    float4v acc[4][4];
#pragma unroll
    for (int i = 0; i < 4; ++i)
#pragma unroll
        for (int j = 0; j < 4; ++j) acc[i][j] = zero;

    for (int k0 = 0; k0 < K; k0 += 64) {
        short8 av[4], bv[4];
#pragma unroll
        for (int it = 0; it < 4; ++it) {
            int e = (it * 256 + tid) * 8;
            int r = e >> 6, c = e & 63;
            av[it] = *(const short8*)(A + (size_t)(row0 + r) * lda + (k0 + c));
            bv[it] = *(const short8*)(B + (size_t)(col0 + r) * ldb + (k0 + c));
        }
        __syncthreads();
#pragma unroll
        for (int it = 0; it < 4; ++it) {
            int e = (it * 256 + tid) * 8;
            *(short8*)&As[e] = av[it];
            *(short8*)&Bs[e] = bv[it];
        }
        __syncthreads();
#pragma unroll
        for (int kk = 0; kk < 64; kk += 32) {
            short8 a_frag[4], b_frag[4];
#pragma unroll
            for (int mi = 0; mi < 4; ++mi)
                a_frag[mi] = *(const short8*)&As[(wm + mi * 16 + frow) * 64 + kk + quad * 8];
#pragma unroll
            for (int ni = 0; ni < 4; ++ni)
                b_frag[ni] = *(const short8*)&Bs[(wn + ni * 16 + frow) * 64 + kk + quad * 8];
#pragma unroll
            for (int mi = 0; mi < 4; ++mi)
#pragma unroll
                for (int ni = 0; ni < 4; ++ni)
                    acc[mi][ni] = __builtin_amdgcn_mfma_f32_16x16x32_bf16(
                        a_frag[mi], b_frag[ni], acc[mi][ni], 0, 0, 0);
        }
        __syncthreads();
    }

#pragma unroll
    for (int mi = 0; mi < 4; ++mi) {
#pragma unroll
        for (int ni = 0; ni < 4; ++ni) {
#pragma unroll
            for (int r = 0; r < 4; ++r) {
                int row = row0 + wm + mi * 16 + quad * 4 + r;
                int col = col0 + wn + ni * 16 + frow;
                size_t g = (size_t)row * N + col;
                float v = acc[mi][ni][r];
                if constexpr (EPI == 0) {
                    outB[g] = f2b(v + biasF[col]);
                } else if constexpr (EPI == 1) {
                    outB[g] = f2b(v + b2f(aux0[g]));
                } else if constexpr (EPI == 2) {
                    float sg = 1.f / (1.f + expf(-v));
                    outB[g] = f2b(sg * b2f(aux0[g]));
                } else if constexpr (EPI == 3) {
                    outF[g] = v + auxF[g];
                } else if constexpr (EPI == 4) {
                    outB[g] = f2b(1.f / (1.f + expf(-v)));
                } else if constexpr (EPI == 5) {
                    float t = v > 0.f ? v : 0.f;
                    outB[g] = f2b(t * t);
                } else if constexpr (EPI == 6) {
                    outF[g] = outF[g] + b2f(aux0[g]) * v;
                }
            }
        }
    }
}

__global__ __launch_bounds__(256) void copy_f32(const float4* __restrict__ src,
                                                float4* __restrict__ dst) {
    size_t g = (size_t)blockIdx.x * 256 + threadIdx.x;
    dst[g] = src[g];
}

// ---------------------------------------------------------------------------
extern "C" void kernel_launch(void* const* d_in, const int* in_sizes, int n_in,
                              void* d_out, int out_size, void* d_ws, size_t ws_size,
                              hipStream_t stream) {
    (void)in_sizes; (void)n_in; (void)out_size; (void)ws_size;
    // ALL inputs are float32 (per reference setup_inputs); output is float32.
    const float* x   = (const float*)d_in[0];
    const float* n1w = (const float*)d_in[1];
    // d_in[2] tm_mix_k, d_in[5] tm_key_w are dead in the reference
    const float* tmv = (const float*)d_in[3];
    const float* tmr = (const float*)d_in[4];
    const float* vw  = (const float*)d_in[6];
    const float* rw  = (const float*)d_in[7];
    const float* ow  = (const float*)d_in[8];
    const float* qw  = (const float*)d_in[9];
    const float* qb  = (const float*)d_in[10];
    const float* skw = (const float*)d_in[11];
    const float* skb = (const float*)d_in[12];
    const float* svw = (const float*)d_in[13];
    const float* svb = (const float*)d_in[14];
    const float* sow = (const float*)d_in[15];
    const float* sob = (const float*)d_in[16];
    const float* n2w = (const float*)d_in[17];
    const float* cmk = (const float*)d_in[18];
    const float* cmr = (const float*)d_in[19];
    const float* ckw = (const float*)d_in[20];
    const float* crw = (const float*)d_in[21];
    const float* cvw = (const float*)d_in[22];

    char* W = (char*)d_ws;
    const size_t MB = 1ull << 20;
    u16*   wsA   = (u16*)(W + 0 * MB);     // 16 MB bf16 activation slot
    u16*   wsB   = (u16*)(W + 16 * MB);    // 16 MB bf16 activation slot
    float* x1    = (float*)(W + 32 * MB);  // 32 MB f32
    float* Kt    = (float*)(W + 64 * MB);  // 2 MB f32
    float* invn  = (float*)(W + 66 * MB);  // 32 KB
    u16*   svw16 = (u16*)(W + 68 * MB);
    u16*   sow16 = (u16*)(W + 70 * MB);
    u16*   vw16  = (u16*)(W + 72 * MB);
    u16*   rw16  = (u16*)(W + 74 * MB);
    u16*   ow16  = (u16*)(W + 76 * MB);
    u16*   crw16 = (u16*)(W + 78 * MB);
    u16*   ckw16 = (u16*)(W + 80 * MB);    // 8 MB
    u16*   cvw16 = (u16*)(W + 88 * MB);    // 8 MB
    u16*   chunk = (u16*)(W + 96 * MB);    // 8 MB (8192x512 bf16)
    float* out   = (float*)d_out;

    dim3 blk(256);
    dim3 gN1024(8, 64);
    dim3 gN512(4, 64);
    const int NW = 512;

    // weight conversions f32 -> bf16
    wcvt<<<NW, blk, 0, stream>>>(svw, svw16, 1024 * 1024);
    wcvt<<<NW, blk, 0, stream>>>(sow, sow16, 1024 * 1024);
    wcvt<<<NW, blk, 0, stream>>>(vw,  vw16,  1024 * 1024);
    wcvt<<<NW, blk, 0, stream>>>(rw,  rw16,  1024 * 1024);
    wcvt<<<NW, blk, 0, stream>>>(ow,  ow16,  1024 * 1024);
    wcvt<<<NW, blk, 0, stream>>>(crw, crw16, 1024 * 1024);
    wcvt<<<NW, blk, 0, stream>>>(ckw, ckw16, 4096 * 1024);
    wcvt<<<NW, blk, 0, stream>>>(cvw, cvw16, 1024 * 4096);

    // --- time-mix ---
    kproj<<<8192, blk, 0, stream>>>(x, n1w, skw, skb, Kt, invn);
    attn_topk<<<8192, blk, 0, stream>>>(x, n1w, qw, qb, Kt, invn, wsB);  // y
    // t = y @ sa_v_w^T + svb
    gemm_bt<0><<<gN1024, blk, 0, stream>>>(wsB, svw16, wsA, nullptr, svb, nullptr, nullptr, 1024, 1024, 1024, 1024);
    // attnO = t @ sa_o_w^T + sob
    gemm_bt<0><<<gN1024, blk, 0, stream>>>(wsA, sow16, wsB, nullptr, sob, nullptr, nullptr, 1024, 1024, 1024, 1024);
    // vin
    mix_shift<<<8192, blk, 0, stream>>>(x, n1w, tmv, wsA);
    // z = vin @ tm_value_w^T + attnO   (in-place over attnO in wsB)
    gemm_bt<1><<<gN1024, blk, 0, stream>>>(wsA, vw16, wsB, nullptr, nullptr, wsB, nullptr, 1024, 1024, 1024, 1024);
    // rin
    mix_shift<<<8192, blk, 0, stream>>>(x, n1w, tmr, wsA);
    // rkv = sigmoid(rin @ tm_recept_w^T) * z   (in-place over z in wsB)
    gemm_bt<2><<<gN1024, blk, 0, stream>>>(wsA, rw16, wsB, nullptr, nullptr, wsB, nullptr, 1024, 1024, 1024, 1024);
    // x1 = x + rkv @ tm_out_w^T   (f32)
    gemm_bt<3><<<gN1024, blk, 0, stream>>>(wsB, ow16, nullptr, x1, nullptr, nullptr, x, 1024, 1024, 1024, 1024);

    // --- channel-mix ---
    mix_shift<<<8192, blk, 0, stream>>>(x1, n2w, cmr, wsA);   // rin2
    // sig2 = sigmoid(rin2 @ cm_recept_w^T)
    gemm_bt<4><<<gN1024, blk, 0, stream>>>(wsA, crw16, wsB, nullptr, nullptr, nullptr, nullptr, 1024, 1024, 1024, 1024);
    mix_shift<<<8192, blk, 0, stream>>>(x1, n2w, cmk, wsA);   // kin2
    for (int c = 0; c < 8; ++c) {
        const u16* ckw_c = ckw16 + (size_t)c * 512 * 1024;  // rows c*512..+512 of (4096,1024)
        const u16* cvw_c = cvw16 + (size_t)c * 512;         // cols c*512..+512 of (1024,4096)
        gemm_bt<5><<<gN512, blk, 0, stream>>>(wsA, ckw_c, chunk, nullptr, nullptr, nullptr, nullptr,
                                              512, 1024, 1024, 1024);
        gemm_bt<6><<<gN1024, blk, 0, stream>>>(chunk, cvw_c, nullptr, x1, nullptr, wsB, nullptr,
                                               1024, 512, 512, 4096);
    }
    // final: out = x1
    copy_f32<<<8192, blk, 0, stream>>>((const float4*)x1, (float4*)d_out);
}